// Round 1
// baseline (678.881 us; speedup 1.0000x reference)
//
#include <hip/hip_runtime.h>
#include <cstddef>

// Problem constants
#define NPTS   65536
#define BATCH  4
#define CH     256
#define HWBINS 64     // 8 x 8
#define KDIM   16384  // HWBINS * CH
#define JDIM   512
#define GSLOTS 64     // slot-spread copies of gemm partials

// k_seg geometry: pure sequential streaming + LDS bin-accumulate (no sort).
#define SEGGRID 256                                  // 1 block/CU
#define SEGTHR  512                                  // 8 waves/block
#define CHUNKS_PER_B   (SEGGRID / BATCH)             // 64 row-chunks per batch
#define ROWS_PER_CHUNK (NPTS / CHUNKS_PER_B)         // 1024 rows per block
#define ROWS_PER_WAVE  (ROWS_PER_CHUNK / (SEGTHR/64))// 128 rows per wave
#define ZERO_F4 (GSLOTS * 2048 / 4)                  // 32768 float4 = 512 KB (out_part only)

// Native clang vector types — __builtin_nontemporal_load requires these.
typedef float vf4 __attribute__((ext_vector_type(4)));
typedef float vf2 __attribute__((ext_vector_type(2)));

__device__ __forceinline__ float2 ntload2(const float* p) {
    vf2 v = __builtin_nontemporal_load((const vf2*)p);
    return make_float2(v.x, v.y);
}

// ---------------------------------------------------------------------------
// Bucketization matching np.searchsorted(np.linspace(-1-eps, 1+eps, 9), x,
// 'right'). np.linspace is float64. (Verified: absmax 6e-5 in prior session.)
// ---------------------------------------------------------------------------
__device__ __forceinline__ int bucket1d(float xf) {
    const double start = -1.0 - 1e-6;
    const double stop  =  1.0 + 1e-6;
    const double step  = (stop - start) / 8.0;
    double x = (double)xf;
    int k = 0;
#pragma unroll
    for (int i = 0; i < 8; ++i) k += ((double)i * step + start <= x) ? 1 : 0;
    k += (stop <= x) ? 1 : 0;
    int b = k - 1;
    return b < 0 ? 0 : (b > 7 ? 7 : b);
}

// Kernel 1: zero out_part (512 KB, the only buffer needing it) + per-point
// bin + per-block histogram. 64 blocks x 256 threads.
__global__ __launch_bounds__(256) void k_bins(const float* __restrict__ coords,
                                              int* __restrict__ bins,
                                              int* __restrict__ hist_blk,
                                              float4* __restrict__ zero4) {
    __shared__ int s_h[HWBINS];
    const int tid = threadIdx.x;
    const int blk = blockIdx.x;
    {
        const float4 z = make_float4(0.f, 0.f, 0.f, 0.f);
        for (int i = blk * 256 + tid; i < ZERO_F4; i += 64 * 256)
            zero4[i] = z;
    }
    if (tid < HWBINS) s_h[tid] = 0;
    __syncthreads();
#pragma unroll
    for (int i = 0; i < 4; ++i) {
        int n = blk * 1024 + i * 256 + tid;
        float2 xy = *(const float2*)(coords + 2 * (size_t)n);
        int bx = bucket1d(xy.x);
        int by = bucket1d(xy.y);
        int bin = by * 8 + bx;   // (kx-1) + (ky-1)*H, H=8
        bins[n] = bin;
        atomicAdd(&s_h[bin], 1);
    }
    __syncthreads();
    if (tid < HWBINS) hist_blk[blk * HWBINS + tid] = s_h[tid];
}

// Kernel 2: one wave. counts[bin] only (no sort -> no offsets needed).
__global__ void k_counts(const int* __restrict__ hist_blk,
                         int* __restrict__ counts) {
    const int b = threadIdx.x;   // 0..63
    int tot = 0;
#pragma unroll 8
    for (int blk = 0; blk < 64; ++blk) tot += hist_blk[blk * HWBINS + b];
    counts[b] = tot;
}

// ---------------------------------------------------------------------------
// Kernel 3: the 256 MB pass, now a PURE SEQUENTIAL STREAM. 256 blocks
// (1/CU, 8 waves), block = (batch, 1024-row chunk). LDS accumulator
// s_acc[64 bins][256 ch] = 64 KB; rows scatter into it via ds_add_f32
// (fire-and-forget, no return). Each wave walks 128 CONTIGUOUS rows
// (128 KB linear region) with 8-deep nontemporal float2 prefetch:
// 8 KB/wave, 64 KB/CU in flight vs ~9 KB needed at 6.3 TB/s.
// Lane owns ch {2L,2L+1,128+2L,129+2L}: ds addresses stride-2 -> cheap
// aliasing, LDS pipe ~15 us << 43 us memory time. Flush: one coalesced
// 64 KB float4 store per block -> partials[256][16384] (16 MB), no atomics.
// ---------------------------------------------------------------------------
__global__ __launch_bounds__(SEGTHR) void k_seg(const float* __restrict__ values,
                                                const int* __restrict__ bins,
                                                float* __restrict__ partials) {
    __shared__ float s_acc[KDIM];   // 64 KB
    const int tid   = threadIdx.x;
    const int b     = blockIdx.x >> 6;        // batch
    const int chunk = blockIdx.x & 63;
    const int r0    = chunk * ROWS_PER_CHUNK;
    {
        float4* s4 = (float4*)s_acc;
        const float4 z = make_float4(0.f, 0.f, 0.f, 0.f);
#pragma unroll
        for (int i = tid; i < KDIM / 4; i += SEGTHR) s4[i] = z;
    }
    __syncthreads();

    const int wid  = tid >> 6;
    const int lane = tid & 63;
    const int wr0  = r0 + wid * ROWS_PER_WAVE;
    const float* vb = values + ((size_t)b * NPTS + wr0) * CH + lane * 2;
    const int*   bp = bins + wr0;

    float2 aA[8], aB[8], nA[8], nB[8];
    int ab[8], nb[8];
#pragma unroll
    for (int j = 0; j < 8; ++j) {
        aA[j] = ntload2(vb + (size_t)j * CH);
        aB[j] = ntload2(vb + (size_t)j * CH + 128);
        ab[j] = bp[j];
    }
#pragma unroll
    for (int g = 0; g < ROWS_PER_WAVE; g += 8) {
        if (g + 8 < ROWS_PER_WAVE) {    // issue next group's loads first
#pragma unroll
            for (int j = 0; j < 8; ++j) {
                nA[j] = ntload2(vb + (size_t)(g + 8 + j) * CH);
                nB[j] = ntload2(vb + (size_t)(g + 8 + j) * CH + 128);
                nb[j] = bp[g + 8 + j];
            }
        }
#pragma unroll
        for (int j = 0; j < 8; ++j) {
            float* d = s_acc + ab[j] * CH + lane * 2;
            atomicAdd(d + 0,   aA[j].x);   // ds_add_f32, no return
            atomicAdd(d + 1,   aA[j].y);
            atomicAdd(d + 128, aB[j].x);
            atomicAdd(d + 129, aB[j].y);
        }
        if (g + 8 < ROWS_PER_WAVE) {
#pragma unroll
            for (int j = 0; j < 8; ++j) {
                aA[j] = nA[j]; aB[j] = nB[j]; ab[j] = nb[j];
            }
        }
    }
    __syncthreads();
    {
        const float4* s4 = (const float4*)s_acc;
        float4* p4 = (float4*)(partials + (size_t)blockIdx.x * KDIM);
#pragma unroll
        for (int i = tid; i < KDIM / 4; i += SEGTHR) p4[i] = s4[i];
    }
}

// ---------------------------------------------------------------------------
// Kernel 4: GEMM partials. 512 blocks (k-chunks of 32, 2/CU), 256 thr.
// Prologue now fuses the 64-chunk partial reduction into the means
// computation (16 MB read, coalesced 128 B per 32-lane group). Main loop
// unchanged from the proven kernel: 32 nontemporal W loads in flight,
// partials into 64 atomic slots.
// ---------------------------------------------------------------------------
__global__ __launch_bounds__(256) void k_gemm_a(const float* __restrict__ Wm,
                                                const float* __restrict__ partials,
                                                const int* __restrict__ counts,
                                                float* __restrict__ out_part) {
    __shared__ float s_m[4 * 32];   // [batch][kk]
    const int tid = threadIdx.x;
    const int kc  = blockIdx.x;     // 0..511
    const int k0  = kc * 32;
    if (tid < 128) {
        int bb = tid >> 5, kk = tid & 31, k = k0 + kk;
        float s = 0.f;
#pragma unroll 8
        for (int c = 0; c < CHUNKS_PER_B; ++c)
            s += partials[(size_t)(bb * CHUNKS_PER_B + c) * KDIM + k];
        float cnt = (float)counts[k >> 8];
        s_m[tid] = s / fmaxf(cnt, 1.0f);
    }
    __syncthreads();

    const float* wp = Wm + (size_t)k0 * JDIM + 2 * tid;
    float2 a0 = {0.f, 0.f}, a1 = {0.f, 0.f}, a2 = {0.f, 0.f}, a3 = {0.f, 0.f};
#pragma unroll
    for (int kk = 0; kk < 32; ++kk) {
        float2 w = ntload2(wp + (size_t)kk * JDIM);
        float m0 = s_m[kk], m1 = s_m[32 + kk], m2 = s_m[64 + kk], m3 = s_m[96 + kk];
        a0.x += m0 * w.x; a0.y += m0 * w.y;
        a1.x += m1 * w.x; a1.y += m1 * w.y;
        a2.x += m2 * w.x; a2.y += m2 * w.y;
        a3.x += m3 * w.x; a3.y += m3 * w.y;
    }
    const int slot = kc & (GSLOTS - 1);
    float* op = out_part + (size_t)slot * 2048 + 2 * tid;
    unsafeAtomicAdd(op + 0,    a0.x); unsafeAtomicAdd(op + 1,    a0.y);
    unsafeAtomicAdd(op + 512,  a1.x); unsafeAtomicAdd(op + 513,  a1.y);
    unsafeAtomicAdd(op + 1024, a2.x); unsafeAtomicAdd(op + 1025, a2.y);
    unsafeAtomicAdd(op + 1536, a3.x); unsafeAtomicAdd(op + 1537, a3.y);
}

// Kernel 5: reduce 64 slots + bias -> out[4][512]. 512 KB read by 8 blocks.
__global__ __launch_bounds__(256) void k_gemm_b(const float* __restrict__ out_part,
                                                const float* __restrict__ bias,
                                                float* __restrict__ out) {
    const int idx = blockIdx.x * 256 + threadIdx.x;   // 0..2047
    const int j = idx & 511;
    float s = bias[j];
#pragma unroll
    for (int sl = 0; sl < GSLOTS; ++sl) s += out_part[(size_t)sl * 2048 + idx];
    out[idx] = s;
}

// ---------------------------------------------------------------------------
extern "C" void kernel_launch(void* const* d_in, const int* in_sizes, int n_in,
                              void* d_out, int out_size, void* d_ws, size_t ws_size,
                              hipStream_t stream) {
    const float* values = (const float*)d_in[0];  // [4, 65536, 256]
    const float* coords = (const float*)d_in[1];  // [65536, 2]
    const float* Wm     = (const float*)d_in[2];  // [16384, 512]
    const float* bias   = (const float*)d_in[3];  // [512]
    float* out = (float*)d_out;                   // [4, 512]

    char* ws = (char*)d_ws;
    // ws layout (bytes), total ~17.3 MB:
    int*   bins     = (int*)(ws + 0);            //  256 KB
    int*   hist_blk = (int*)(ws + 262144);       //   16 KB
    int*   counts   = (int*)(ws + 278528);       //  256 B
    float* out_part = (float*)(ws + 278784);     //  512 KB  [64][2048]
    float* partials = (float*)(ws + 803072);     //   16 MB  [256][16384]

    k_bins  <<<64, 256, 0, stream>>>(coords, bins, hist_blk, (float4*)out_part);
    k_counts<<<1, 64, 0, stream>>>(hist_blk, counts);
    k_seg   <<<SEGGRID, SEGTHR, 0, stream>>>(values, bins, partials);
    k_gemm_a<<<512, 256, 0, stream>>>(Wm, partials, counts, out_part);
    k_gemm_b<<<8, 256, 0, stream>>>(out_part, bias, out);
}